// Round 7
// baseline (520.857 us; speedup 1.0000x reference)
//
#include <hip/hip_runtime.h>
#include <hip/hip_bf16.h>
#include <hip/hip_fp16.h>
#include <cmath>

#define N_NODES 50000
#define N_EDGES 800000
#define HID 64
#define HEADS 4
#define CONVS 2
#define CLS 16
#define SLOPE 0.2f
#define SCAN_B 1024
#define LOG2E 1.4426950408889634f

typedef unsigned int  uint32;
typedef unsigned short ushort16;

__device__ __forceinline__ ushort16 f2bf(float x) {
    union { float f; uint32 u; } v; v.f = x;
    uint32 r = v.u + 0x7fffu + ((v.u >> 16) & 1u);   // RNE
    return (ushort16)(r >> 16);
}
__device__ __forceinline__ float bf_lo(uint32 w) { return __uint_as_float(w << 16); }
__device__ __forceinline__ float bf_hi(uint32 w) { return __uint_as_float(w & 0xffff0000u); }

// ---------------- CSR build ----------------

__global__ void hist_kernel(const int* __restrict__ dst, int* __restrict__ deg) {
    int e = blockIdx.x * blockDim.x + threadIdx.x;
    if (e < N_EDGES) atomicAdd(&deg[dst[e]], 1);
}

__global__ void scan1_kernel(const int* __restrict__ deg, int* __restrict__ row_ptr,
                             int* __restrict__ tops) {
    __shared__ int buf[SCAN_B];
    int i = blockIdx.x * SCAN_B + threadIdx.x;
    int v = (i < N_NODES) ? deg[i] : 0;
    buf[threadIdx.x] = v;
    __syncthreads();
    for (int off = 1; off < SCAN_B; off <<= 1) {
        int t = (threadIdx.x >= off) ? buf[threadIdx.x - off] : 0;
        __syncthreads();
        buf[threadIdx.x] += t;
        __syncthreads();
    }
    if (i < N_NODES) row_ptr[i + 1] = buf[threadIdx.x];
    if (threadIdx.x == SCAN_B - 1) tops[blockIdx.x] = buf[threadIdx.x];
}

__global__ void scan2_kernel(int* __restrict__ tops, int nb) {
    if (threadIdx.x == 0 && blockIdx.x == 0) {
        int acc = 0;
        for (int b = 0; b < nb; b++) { int t = tops[b]; tops[b] = acc; acc += t; }
    }
}

__global__ void scan3_kernel(int* __restrict__ row_ptr, const int* __restrict__ tops) {
    int i = blockIdx.x * SCAN_B + threadIdx.x;
    if (i < N_NODES) row_ptr[i + 1] += tops[blockIdx.x];
    if (i == 0 && blockIdx.x == 0) row_ptr[0] = 0;
}

__global__ void scatter_kernel(const int* __restrict__ src, const int* __restrict__ dst,
                               const int* __restrict__ row_ptr, int* __restrict__ cursor,
                               int* __restrict__ col) {
    int e = blockIdx.x * blockDim.x + threadIdx.x;
    if (e < 8) col[N_EDGES + e] = 0;   // pad for unclamped prefetch
    if (e < N_EDGES) {
        int d = dst[e];
        int pos = row_ptr[d] + atomicAdd(&cursor[d], 1);
        col[pos] = src[e];
    }
}

// ---------------- per-type projection: h = feat @ W1 + b1 (+ bf16 copy, rowsum) --------

__global__ __launch_bounds__(256)
void proj_kernel(const float* __restrict__ feat, const float* __restrict__ W,
                 const float* __restrict__ b, float* __restrict__ h,
                 ushort16* __restrict__ hb, float* __restrict__ s_out,
                 int rows, int K, int base_row) {
    int lane = threadIdx.x & 63;
    int wid  = threadIdx.x >> 6;
    int r = blockIdx.x * 4 + wid;
    if (r >= rows) return;
    const float* arow = feat + (size_t)r * K;
    float acc = b[lane];
    for (int kk = 0; kk < K; kk += 4) {
        float4 a4 = *reinterpret_cast<const float4*>(arow + kk);
        acc = fmaf(a4.x, W[(kk + 0) * 64 + lane], acc);
        acc = fmaf(a4.y, W[(kk + 1) * 64 + lane], acc);
        acc = fmaf(a4.z, W[(kk + 2) * 64 + lane], acc);
        acc = fmaf(a4.w, W[(kk + 3) * 64 + lane], acc);
    }
    int gr = base_row + r;
    h[(size_t)gr * 64 + lane]  = acc;
    hb[(size_t)gr * 64 + lane] = f2bf(acc);
    float ssum = acc;
    #pragma unroll
    for (int off = 32; off; off >>= 1) ssum += __shfl_xor(ssum, off);
    if (lane == 0) s_out[gr] = ssum;
}

// ------- conv 0: 2 waves/node edge-split, no max-shift, 1-deep unclamped prefetch -------

__global__ __launch_bounds__(256)
void conv0_kernel(const ushort16* __restrict__ hb, const float* __restrict__ s_h,
                  const float* __restrict__ al, const float* __restrict__ ar,
                  const int* __restrict__ row_ptr, const int* __restrict__ col,
                  ushort16* __restrict__ x1p, float4* __restrict__ s1p) {
    __shared__ float red[2][8][64];
    int lane = threadIdx.x & 63;
    int wid  = threadIdx.x >> 6;
    int slot = wid >> 1;             // node within block (0/1)
    int wsub = wid & 1;              // wave within node (0/1)
    int n = blockIdx.x * 2 + slot;   // N_NODES even -> always valid

    float sd = s_h[n];
    int base = row_ptr[n];
    int deg  = row_ptr[n + 1] - base;

    float alk[HEADS], ck[HEADS], alkB[HEADS], ckB[HEADS];
    float den[HEADS] = {0.f, 0.f, 0.f, 0.f}, num[HEADS] = {0.f, 0.f, 0.f, 0.f};
    #pragma unroll
    for (int hd = 0; hd < HEADS; hd++) {
        float a = al[(hd * CONVS + 0) * 64 + lane] * LOG2E;
        float c = ar[(hd * CONVS + 0) * 64 + lane] * LOG2E * sd;
        alk[hd] = a; ck[hd] = c; alkB[hd] = SLOPE * a; ckB[hd] = SLOPE * c;
    }

    int half = (deg + 1) >> 1;
    int jb = wsub ? half : 0;
    int je = wsub ? deg  : half;
    const char* xb = (const char*)hb + (size_t)lane * 2;   // 2B/lane, row = 128B

    if (jb < je) {
        int c0 = col[base + jb];
        float sv = s_h[c0];
        uint32 hv = (uint32)*reinterpret_cast<const ushort16*>(xb + (size_t)c0 * 128);
        for (int j = jb; j < je; j++) {
            int cn = col[base + j + 1];          // padded; may read neighbor row (safe)
            float sn = s_h[cn];
            uint32 hn = (uint32)*reinterpret_cast<const ushort16*>(xb + (size_t)cn * 128);
            float hf = __uint_as_float(hv << 16);
            #pragma unroll
            for (int hd = 0; hd < HEADS; hd++) {
                float w = exp2f(fmaxf(fmaf(alk[hd], sv, ck[hd]), fmaf(alkB[hd], sv, ckB[hd])));
                den[hd] += w;
                num[hd] = fmaf(hf, w, num[hd]);
            }
            sv = sn; hv = hn;
        }
    }

    if (wsub == 1) {
        #pragma unroll
        for (int hd = 0; hd < HEADS; hd++) {
            red[slot][hd][lane]     = num[hd];
            red[slot][4 + hd][lane] = den[hd];
        }
    }
    __syncthreads();
    if (wsub == 0) {
        float o[HEADS];
        #pragma unroll
        for (int hd = 0; hd < HEADS; hd++) {
            float nn = num[hd] + red[slot][hd][lane];
            float dd = den[hd] + red[slot][4 + hd][lane];
            o[hd] = nn / dd;
        }
        uint32 lo = ((uint32)f2bf(o[0])) | (((uint32)f2bf(o[1])) << 16);
        uint32 hi = ((uint32)f2bf(o[2])) | (((uint32)f2bf(o[3])) << 16);
        *reinterpret_cast<uint2*>(x1p + ((size_t)n * 64 + lane) * 4) = make_uint2(lo, hi);

        float s0 = o[0], s1v = o[1], s2 = o[2], s3 = o[3];
        #pragma unroll
        for (int off = 32; off; off >>= 1) {
            s0 += __shfl_xor(s0, off); s1v += __shfl_xor(s1v, off);
            s2 += __shfl_xor(s2, off); s3  += __shfl_xor(s3, off);
        }
        if (lane == 0) s1p[n] = make_float4(s0, s1v, s2, s3);
    }
}

// ------- conv 1: 2 waves/node edge-split, no max-shift; writes packed fp16 z -------

__global__ __launch_bounds__(256)
void conv1_kernel(const float* __restrict__ h, const ushort16* __restrict__ x1p,
                  const float4* __restrict__ s1p,
                  const float* __restrict__ al, const float* __restrict__ ar,
                  const int* __restrict__ row_ptr, const int* __restrict__ col,
                  uint2* __restrict__ zh /* [N][64 lanes][4 heads] fp16 */) {
    __shared__ float red[2][8][64];
    int lane = threadIdx.x & 63;
    int wid  = threadIdx.x >> 6;
    int slot = wid >> 1;
    int wsub = wid & 1;
    int n = blockIdx.x * 2 + slot;

    int base = row_ptr[n];
    int deg  = row_ptr[n + 1] - base;

    float4 sdn = s1p[n];
    float sdv[HEADS] = {sdn.x, sdn.y, sdn.z, sdn.w};
    float alk[HEADS], ck[HEADS], alkB[HEADS], ckB[HEADS];
    float den[HEADS] = {0.f, 0.f, 0.f, 0.f}, num[HEADS] = {0.f, 0.f, 0.f, 0.f};
    #pragma unroll
    for (int hd = 0; hd < HEADS; hd++) {
        float a = al[(hd * CONVS + 1) * 64 + lane] * LOG2E;
        float c = ar[(hd * CONVS + 1) * 64 + lane] * LOG2E * sdv[hd];
        alk[hd] = a; ck[hd] = c; alkB[hd] = SLOPE * a; ckB[hd] = SLOPE * c;
    }

    int half = (deg + 1) >> 1;
    int jb = wsub ? half : 0;
    int je = wsub ? deg  : half;
    const char* xb = (const char*)x1p + (size_t)lane * 8;   // 8B/lane, row = 512B

    if (jb < je) {
        int c0 = col[base + jb];
        float4 sv4 = s1p[c0];
        uint2 xv = *reinterpret_cast<const uint2*>(xb + (size_t)c0 * 512);
        for (int j = jb; j < je; j++) {
            int cn = col[base + j + 1];
            float4 sn4 = s1p[cn];
            uint2 xn = *reinterpret_cast<const uint2*>(xb + (size_t)cn * 512);
            float xf[HEADS] = {bf_lo(xv.x), bf_hi(xv.x), bf_lo(xv.y), bf_hi(xv.y)};
            float sf[HEADS] = {sv4.x, sv4.y, sv4.z, sv4.w};
            #pragma unroll
            for (int hd = 0; hd < HEADS; hd++) {
                float w = exp2f(fmaxf(fmaf(alk[hd], sf[hd], ck[hd]), fmaf(alkB[hd], sf[hd], ckB[hd])));
                den[hd] += w;
                num[hd] = fmaf(xf[hd], w, num[hd]);
            }
            sv4 = sn4; xv = xn;
        }
    }

    if (wsub == 1) {
        #pragma unroll
        for (int hd = 0; hd < HEADS; hd++) {
            red[slot][hd][lane]     = num[hd];
            red[slot][4 + hd][lane] = den[hd];
        }
    }
    __syncthreads();
    if (wsub == 0) {
        float hres = h[(size_t)n * 64 + lane];
        float z[HEADS];
        #pragma unroll
        for (int hd = 0; hd < HEADS; hd++) {
            float nn = num[hd] + red[slot][hd][lane];
            float dd = den[hd] + red[slot][4 + hd][lane];
            z[hd] = fmaxf(hres + nn / dd, 0.f);
        }
        __half2 p01 = __floats2half2_rn(z[0], z[1]);
        __half2 p23 = __floats2half2_rn(z[2], z[3]);
        uint2 pk;
        pk.x = *reinterpret_cast<uint32*>(&p01);
        pk.y = *reinterpret_cast<uint32*>(&p23);
        zh[(size_t)n * 64 + lane] = pk;   // coalesced 512B per wave
    }
}

// ------- W2 reorder to match z packing: W2r[(q*4+hd)*64+col] = W2[(hd*64+q)*64+col] ----

__global__ void w2r_kernel(const float* __restrict__ W2, float* __restrict__ W2r) {
    int col = threadIdx.x;         // 64
    int idx = blockIdx.x;          // 256 = q*4+hd
    int q = idx >> 2, hd = idx & 3;
    W2r[idx * 64 + col] = W2[(hd * 64 + q) * 64 + col];
}

// ------- encoded = z @ W2 + b2 (streaming GEMM, no shuffles; 4 rows/wave) -------

__global__ __launch_bounds__(256)
void zgemm_kernel(const uint2* __restrict__ zh, const float* __restrict__ W2r,
                  const float* __restrict__ b2, float* __restrict__ out_encoded) {
    int lane = threadIdx.x & 63;
    int wid  = threadIdx.x >> 6;
    int r0 = (blockIdx.x * 4 + wid) * 4;      // 4 rows per wave
    if (r0 >= N_NODES) return;

    float bb = b2[lane];
    float a0 = bb, a1 = bb, a2 = bb, a3 = bb;
    const uint2* z0 = zh + (size_t)r0 * 64;

    for (int q = 0; q < 64; q += 2) {
        float w[8];
        const float* wp = W2r + (q * 4) * 64 + lane;
        #pragma unroll
        for (int t = 0; t < 8; t++) w[t] = wp[t * 64];

        #pragma unroll
        for (int rr = 0; rr < 4; rr++) {
            uint4 zz = *reinterpret_cast<const uint4*>(z0 + rr * 64 + q);
            float2 fA = __half22float2(*reinterpret_cast<const __half2*>(&zz.x));
            float2 fB = __half22float2(*reinterpret_cast<const __half2*>(&zz.y));
            float2 fC = __half22float2(*reinterpret_cast<const __half2*>(&zz.z));
            float2 fD = __half22float2(*reinterpret_cast<const __half2*>(&zz.w));
            float acc = (rr == 0) ? a0 : (rr == 1) ? a1 : (rr == 2) ? a2 : a3;
            acc = fmaf(fA.x, w[0], acc);
            acc = fmaf(fA.y, w[1], acc);
            acc = fmaf(fB.x, w[2], acc);
            acc = fmaf(fB.y, w[3], acc);
            acc = fmaf(fC.x, w[4], acc);
            acc = fmaf(fC.y, w[5], acc);
            acc = fmaf(fD.x, w[6], acc);
            acc = fmaf(fD.y, w[7], acc);
            if (rr == 0) a0 = acc; else if (rr == 1) a1 = acc; else if (rr == 2) a2 = acc; else a3 = acc;
        }
    }
    out_encoded[(size_t)(r0 + 0) * 64 + lane] = a0;
    out_encoded[(size_t)(r0 + 1) * 64 + lane] = a1;
    out_encoded[(size_t)(r0 + 2) * 64 + lane] = a2;
    out_encoded[(size_t)(r0 + 3) * 64 + lane] = a3;
}

// ------- logits = relu(encoded) @ W3 + b3 -------

__global__ __launch_bounds__(256)
void logits_kernel(const float* __restrict__ enc, const float* __restrict__ W3,
                   const float* __restrict__ b3, float* __restrict__ out_logits) {
    int t = blockIdx.x * 256 + threadIdx.x;
    int r = t >> 4, c = t & 15;
    if (r >= N_NODES) return;
    float acc = b3[c];
    const float* er = enc + (size_t)r * 64;
    #pragma unroll 8
    for (int k = 0; k < 64; k++)
        acc = fmaf(fmaxf(er[k], 0.f), W3[k * CLS + c], acc);
    out_logits[(size_t)r * CLS + c] = acc;
}

// ---------------- launch ----------------

extern "C" void kernel_launch(void* const* d_in, const int* in_sizes, int n_in,
                              void* d_out, int out_size, void* d_ws, size_t ws_size,
                              hipStream_t stream) {
    const float* feat0 = (const float*)d_in[0];
    const float* feat1 = (const float*)d_in[1];
    const float* feat2 = (const float*)d_in[2];
    const int*   src   = (const int*)d_in[3];
    const int*   dst   = (const int*)d_in[4];
    const float* W1_0  = (const float*)d_in[5];
    const float* b1_0  = (const float*)d_in[6];
    const float* W1_1  = (const float*)d_in[7];
    const float* b1_1  = (const float*)d_in[8];
    const float* W1_2  = (const float*)d_in[9];
    const float* b1_2  = (const float*)d_in[10];
    const float* al    = (const float*)d_in[11];
    const float* ar    = (const float*)d_in[12];
    const float* W2    = (const float*)d_in[13];
    const float* b2    = (const float*)d_in[14];
    const float* W3    = (const float*)d_in[15];
    const float* b3    = (const float*)d_in[16];

    float* out_logits  = (float*)d_out;
    float* out_encoded = (float*)d_out + (size_t)N_NODES * CLS;

    char* ws = (char*)d_ws;
    size_t off = 0;
    auto alloc = [&](size_t bytes) {
        void* p = ws + off;
        off = (off + bytes + 255) & ~(size_t)255;
        return p;
    };
    int*      row_ptr = (int*)alloc((N_NODES + 1) * sizeof(int));
    int*      deg     = (int*)alloc(N_NODES * sizeof(int));
    int*      tops    = (int*)alloc(64 * sizeof(int));
    int*      col     = (int*)alloc(((size_t)N_EDGES + 8) * sizeof(int));
    float*    h       = (float*)alloc((size_t)N_NODES * 64 * sizeof(float));
    ushort16* hb      = (ushort16*)alloc((size_t)N_NODES * 64 * sizeof(ushort16));
    float*    s_h     = (float*)alloc(N_NODES * sizeof(float));
    ushort16* x1p     = (ushort16*)alloc((size_t)N_NODES * 64 * 4 * sizeof(ushort16));
    float4*   s1p     = (float4*)alloc(N_NODES * sizeof(float4));
    uint2*    zh      = (uint2*)alloc((size_t)N_NODES * 64 * sizeof(uint2));
    float*    W2r     = (float*)alloc(256 * 64 * sizeof(float));
    (void)ws_size; (void)in_sizes; (void)n_in; (void)out_size;

    // CSR by dst
    (void)hipMemsetAsync(deg, 0, N_NODES * sizeof(int), stream);
    hist_kernel<<<(N_EDGES + 255) / 256, 256, 0, stream>>>(dst, deg);
    int nb = (N_NODES + SCAN_B - 1) / SCAN_B;
    scan1_kernel<<<nb, SCAN_B, 0, stream>>>(deg, row_ptr, tops);
    scan2_kernel<<<1, 64, 0, stream>>>(tops, nb);
    scan3_kernel<<<nb, SCAN_B, 0, stream>>>(row_ptr, tops);
    (void)hipMemsetAsync(deg, 0, N_NODES * sizeof(int), stream);
    scatter_kernel<<<(N_EDGES + 255) / 256, 256, 0, stream>>>(src, dst, row_ptr, deg, col);

    // W2 reorder (independent; overlaps with CSR tail)
    w2r_kernel<<<256, 64, 0, stream>>>(W2, W2r);

    // projections
    proj_kernel<<<(20000 + 3) / 4, 256, 0, stream>>>(feat0, W1_0, b1_0, h, hb, s_h, 20000, 256, 0);
    proj_kernel<<<(15000 + 3) / 4, 256, 0, stream>>>(feat1, W1_1, b1_1, h, hb, s_h, 15000, 128, 20000);
    proj_kernel<<<(15000 + 3) / 4, 256, 0, stream>>>(feat2, W1_2, b1_2, h, hb, s_h, 15000, 64, 35000);

    // convs (2 nodes per block, 2 waves per node)
    conv0_kernel<<<N_NODES / 2, 256, 0, stream>>>(hb, s_h, al, ar, row_ptr, col, x1p, s1p);
    conv1_kernel<<<N_NODES / 2, 256, 0, stream>>>(h, x1p, s1p, al, ar, row_ptr, col, zh);

    // epilogue GEMMs
    zgemm_kernel<<<(N_NODES / 16), 256, 0, stream>>>(zh, W2r, b2, out_encoded);
    logits_kernel<<<(N_NODES * CLS + 255) / 256, 256, 0, stream>>>(out_encoded, W3, b3, out_logits);
}